// Round 12
// baseline (192.297 us; speedup 1.0000x reference)
//
#include <hip/hip_runtime.h>

#define FLOOR_EPS 1e-6f

typedef float f32x4 __attribute__((ext_vector_type(4)));

constexpr int Bn     = 64;
constexpr int Tn     = 4096;
constexpr int Cn     = 80;
constexpr int G      = Cn / 4;     // 20 float4 channel-groups
constexpr int P      = 16;         // slabs per row
constexpr int SLAB   = Tn / P;     // 256 timesteps per slab
constexpr int KC     = 16;         // chunks per slab
constexpr int CH     = SLAB / KC;  // 16 timesteps per chunk
constexpr int NT     = KC * G;     // 320 threads (5 waves) for kernel A
constexpr int NCHUNK = Tn / CH;    // 256 chunks per row
constexpr int TOT    = Bn * NCHUNK * G;   // 327,680 threads for kernel B

__device__ __forceinline__ void nt_store4(float4* p, float a, float b,
                                          float c, float d) {
    f32x4 v = {a, b, c, d};
    __builtin_nontemporal_store(v, (f32x4*)p);
}

// ---------------- Kernel A: per-slab scan, write ALL per-chunk states -------
// (r10-proven, ~14 us.) One block per (b,p) slab. Phase 1: stream 16-step
// chunk EMA summaries. Phase 2: 4-round weighted Hillis-Steele (weight d^16).
// Writes the slab-LOCAL inclusive state per chunk (2.6 MB).
__global__ __launch_bounds__(NT, 6)
void pcen_slabsum_kernel(const float* __restrict__ x,
                         const float* __restrict__ smooth,
                         float4* __restrict__ states)   // [Bn*NCHUNK*G]
{
    __shared__ float4 sc[2][KC][G];

    const int p  = blockIdx.x % P;
    const int b  = blockIdx.x / P;
    const int t  = threadIdx.x;
    const int g  = t % G;            // g fastest -> coalesced 320B runs
    const int kc = t / G;

    const float4 smv = ((const float4*)smooth)[g];
    float w0 = fminf(fmaxf(smv.x, 0.f), 1.f), w1 = fminf(fmaxf(smv.y, 0.f), 1.f);
    float w2 = fminf(fmaxf(smv.z, 0.f), 1.f), w3 = fminf(fmaxf(smv.w, 0.f), 1.f);
    float d0 = 1.f - w0, d1 = 1.f - w1, d2 = 1.f - w2, d3 = 1.f - w3;

    // d^16 via 4 squarings
    float q0 = d0 * d0, q1 = d1 * d1, q2 = d2 * d2, q3 = d3 * d3;
    q0 *= q0; q1 *= q1; q2 *= q2; q3 *= q3;
    q0 *= q0; q1 *= q1; q2 *= q2; q3 *= q3;
    q0 *= q0; q1 *= q1; q2 *= q2; q3 *= q3;

    const size_t rowbase = ((size_t)b * Tn + (size_t)p * SLAB + (size_t)kc * CH) * G + g;
    const float4* px = (const float4*)x + rowbase;

    // phase 1: chunk summary (fold init into very first chunk: e=x0 works
    // because d*x0 + w*x0 == x0)
    const bool fc = (p == 0) && (kc == 0);
    float e0, e1, e2, e3;
    if (fc) { float4 v = px[0]; e0 = v.x; e1 = v.y; e2 = v.z; e3 = v.w; }
    else    { e0 = 0.f; e1 = 0.f; e2 = 0.f; e3 = 0.f; }
    #pragma unroll
    for (int u = 0; u < CH; ++u) {
        float4 v = px[(size_t)u * G];
        e0 = fmaf(d0, e0, w0 * v.x);
        e1 = fmaf(d1, e1, w1 * v.y);
        e2 = fmaf(d2, e2, w2 * v.z);
        e3 = fmaf(d3, e3, w3 * v.w);
    }
    sc[0][kc][g] = make_float4(e0, e1, e2, e3);
    __syncthreads();

    // phase 2: weighted scan over chunks (W starts d^16, squared per round)
    float W0 = q0, W1 = q1, W2 = q2, W3 = q3;
    int src = 0;
    #pragma unroll
    for (int off = 1; off < KC; off <<= 1) {
        float4 v = sc[src][kc][g];
        if (kc >= off) {
            float4 u4 = sc[src][kc - off][g];
            v.x = fmaf(W0, u4.x, v.x);
            v.y = fmaf(W1, u4.y, v.y);
            v.z = fmaf(W2, u4.z, v.z);
            v.w = fmaf(W3, u4.w, v.w);
        }
        sc[src ^ 1][kc][g] = v;
        __syncthreads();
        src ^= 1;
        W0 *= W0; W1 *= W1; W2 *= W2; W3 *= W3;
    }

    // write every chunk's slab-local inclusive state, fully coalesced:
    // index = (b*NCHUNK + p*KC + kc)*G + g = blockIdx.x*NT + t
    states[(size_t)blockIdx.x * NT + t] = sc[src][kc][g];
}

// ---------------- Kernel B: barrier-free streaming replay -------------------
// Flat 256-thread blocks, NO LDS, NO __syncthreads (so no vmcnt-drain
// points). Per thread: (1) issue the first 8 x-loads immediately (32 VGPRs
// retained - fits the 102-reg budget, unlike r6's 64-float4 spill), (2)
// batched-parallel prefix fold over predecessor slab summaries (3 batches
// of 5 loads -> 3 L2 round-trips instead of r4's 15 chained), (3) replay:
// first 8 steps from registers, last 8 streamed, nontemporal stores.
__global__ __launch_bounds__(256, 5)
void pcen_out_kernel(const float* __restrict__ x,
                     const float* __restrict__ alpha,
                     const float* __restrict__ delta,
                     const float* __restrict__ root,
                     const float* __restrict__ smooth,
                     const float4* __restrict__ states,
                     float* __restrict__ out)
{
    const int tid = blockIdx.x * blockDim.x + threadIdx.x;
    if (tid >= TOT) return;
    const int g = tid % G;
    const int k = (tid / G) % NCHUNK;
    const int b = tid / (G * NCHUNK);
    const int p  = k >> 4;     // slab
    const int kc = k & 15;     // chunk within slab

    const size_t rowbase = ((size_t)b * Tn + (size_t)k * CH) * G + g;
    const float4* px = (const float4*)x + rowbase;

    // ---- (1) issue first-8 x loads NOW; they arrive during the prologue ----
    float4 xe[8];
    #pragma unroll
    for (int u = 0; u < 8; ++u) xe[u] = px[(size_t)u * G];

    // exclusive slab-local state of chunk kc-1 (states[tid] = this chunk)
    float4 ex = make_float4(0.f, 0.f, 0.f, 0.f);
    if (kc > 0) ex = states[(size_t)tid - G];

    // ---- per-channel params ----
    const float4 smv = ((const float4*)smooth)[g];
    float w0 = fminf(fmaxf(smv.x, 0.f), 1.f), w1 = fminf(fmaxf(smv.y, 0.f), 1.f);
    float w2 = fminf(fmaxf(smv.z, 0.f), 1.f), w3 = fminf(fmaxf(smv.w, 0.f), 1.f);
    float d0 = 1.f - w0, d1 = 1.f - w1, d2 = 1.f - w2, d3 = 1.f - w3;

    // d^16 via 4 squarings; d^256 via 4 more
    float q0 = d0 * d0, q1 = d1 * d1, q2 = d2 * d2, q3 = d3 * d3;
    q0 *= q0; q1 *= q1; q2 *= q2; q3 *= q3;
    q0 *= q0; q1 *= q1; q2 *= q2; q3 *= q3;
    q0 *= q0; q1 *= q1; q2 *= q2; q3 *= q3;
    float W0 = q0, W1 = q1, W2 = q2, W3 = q3;
    W0 *= W0; W1 *= W1; W2 *= W2; W3 *= W3;
    W0 *= W0; W1 *= W1; W2 *= W2; W3 *= W3;
    W0 *= W0; W1 *= W1; W2 *= W2; W3 *= W3;
    W0 *= W0; W1 *= W1; W2 *= W2; W3 *= W3;

    // ---- (2) batched-parallel prefix fold over slabs q = 0..p-1 ----
    // summary of slab q = states[(b*NCHUNK + q*KC + KC-1)*G + g]
    float S0 = 0.f, S1 = 0.f, S2 = 0.f, S3 = 0.f;
    {
        const size_t rb = (size_t)b * NCHUNK;
        #pragma unroll
        for (int B0 = 0; B0 < P - 1; B0 += 5) {
            float4 buf[5];
            #pragma unroll
            for (int j = 0; j < 5; ++j) {
                const int q = B0 + j;
                if (q < p)
                    buf[j] = states[(rb + (size_t)q * KC + (KC - 1)) * G + g];
            }
            #pragma unroll
            for (int j = 0; j < 5; ++j) {
                const int q = B0 + j;
                if (q < p) {
                    S0 = fmaf(W0, S0, buf[j].x);
                    S1 = fmaf(W1, S1, buf[j].y);
                    S2 = fmaf(W2, S2, buf[j].z);
                    S3 = fmaf(W3, S3, buf[j].w);
                }
            }
        }
    }

    // ---- incoming state m = (d^16)^kc * S + local_exclusive ----
    float m0, m1, m2, m3;
    if (kc == 0) {
        m0 = S0; m1 = S1; m2 = S2; m3 = S3;
    } else {
        // (d^16)^kc via square-and-multiply on 4 bits of kc
        float k0 = 1.f, k1 = 1.f, k2 = 1.f, k3 = 1.f;
        float b0 = q0, b1 = q1, b2 = q2, b3 = q3;
        int kk = kc;
        #pragma unroll
        for (int bit = 0; bit < 4; ++bit) {
            if (kk & 1) { k0 *= b0; k1 *= b1; k2 *= b2; k3 *= b3; }
            b0 *= b0; b1 *= b1; b2 *= b2; b3 *= b3;
            kk >>= 1;
        }
        m0 = fmaf(k0, S0, ex.x);
        m1 = fmaf(k1, S1, ex.y);
        m2 = fmaf(k2, S2, ex.z);
        m3 = fmaf(k3, S3, ex.w);
    }
    if (k == 0) {   // exact folded init: a_0 = x_0
        m0 = xe[0].x; m1 = xe[0].y; m2 = xe[0].z; m3 = xe[0].w;
    }

    // ---- pointwise params ----
    const float4 alv = ((const float4*)alpha)[g];
    const float4 dlv = ((const float4*)delta)[g];
    const float4 rov = ((const float4*)root)[g];
    float nega[4], invr[4], dl[4], sub[4];
    {
        float as[4] = {alv.x, alv.y, alv.z, alv.w};
        float rs[4] = {rov.x, rov.y, rov.z, rov.w};
        dl[0] = dlv.x; dl[1] = dlv.y; dl[2] = dlv.z; dl[3] = dlv.w;
        #pragma unroll
        for (int j = 0; j < 4; ++j) {
            nega[j] = -fminf(as[j], 1.f);
            invr[j] = 1.f / fmaxf(rs[j], 1.f);
            sub[j]  = __expf(invr[j] * __logf(dl[j]));   // delta^(1/r)
        }
    }
    const bool all_sqrt = (invr[0] == 0.5f) & (invr[1] == 0.5f) &
                          (invr[2] == 0.5f) & (invr[3] == 0.5f);

    float4* po = (float4*)out + rowbase;

    // ---- (3) replay: first 8 from registers, last 8 streamed ----
    if (all_sqrt) {   // root == 2 fast path (wave-uniform)
        #pragma unroll
        for (int u = 0; u < CH; ++u) {
            float4 xv = (u < 8) ? xe[u] : px[(size_t)u * G];
            m0 = fmaf(d0, m0, w0 * xv.x);
            m1 = fmaf(d1, m1, w1 * xv.y);
            m2 = fmaf(d2, m2, w2 * xv.z);
            m3 = fmaf(d3, m3, w3 * xv.w);
            nt_store4(&po[(size_t)u * G],
                sqrtf(fmaf(xv.x, __expf(nega[0] * __logf(FLOOR_EPS + m0)), dl[0])) - sub[0],
                sqrtf(fmaf(xv.y, __expf(nega[1] * __logf(FLOOR_EPS + m1)), dl[1])) - sub[1],
                sqrtf(fmaf(xv.z, __expf(nega[2] * __logf(FLOOR_EPS + m2)), dl[2])) - sub[2],
                sqrtf(fmaf(xv.w, __expf(nega[3] * __logf(FLOOR_EPS + m3)), dl[3])) - sub[3]);
        }
    } else {
        float w[4] = {w0, w1, w2, w3}, dc[4] = {d0, d1, d2, d3};
        float mm[4] = {m0, m1, m2, m3};
        #pragma unroll
        for (int u = 0; u < CH; ++u) {
            float4 xv = (u < 8) ? xe[u] : px[(size_t)u * G];
            float xv4[4] = {xv.x, xv.y, xv.z, xv.w};
            float os[4];
            #pragma unroll
            for (int j = 0; j < 4; ++j) {
                mm[j]   = fmaf(dc[j], mm[j], w[j] * xv4[j]);
                float pw = __expf(nega[j] * __logf(FLOOR_EPS + mm[j]));
                float v  = fmaf(xv4[j], pw, dl[j]);
                os[j]    = __expf(invr[j] * __logf(v)) - sub[j];
            }
            nt_store4(&po[(size_t)u * G], os[0], os[1], os[2], os[3]);
        }
    }
}

extern "C" void kernel_launch(void* const* d_in, const int* in_sizes, int n_in,
                              void* d_out, int out_size, void* d_ws, size_t ws_size,
                              hipStream_t stream) {
    const float* x      = (const float*)d_in[0];
    const float* alpha  = (const float*)d_in[1];
    const float* delta  = (const float*)d_in[2];
    const float* root   = (const float*)d_in[3];
    const float* smooth = (const float*)d_in[4];
    float* out = (float*)d_out;

    float4* states = (float4*)d_ws;   // Bn*NCHUNK*G float4 = 2.62 MB

    pcen_slabsum_kernel<<<Bn * P, NT, 0, stream>>>(x, smooth, states);

    int block = 256;
    int gridB = (TOT + block - 1) / block;   // 1280 blocks
    pcen_out_kernel<<<gridB, block, 0, stream>>>(x, alpha, delta, root, smooth,
                                                 states, out);
}

// Round 13
// 172.002 us; speedup vs baseline: 1.1180x; 1.1180x over previous
//
#include <hip/hip_runtime.h>

#define FLOOR_EPS 1e-6f

typedef float f32x4 __attribute__((ext_vector_type(4)));

constexpr int Bn     = 64;
constexpr int Tn     = 4096;
constexpr int Cn     = 80;
constexpr int G      = Cn / 4;     // 20 float4 channel-groups
constexpr int P      = 16;         // slabs per row
constexpr int SLAB   = Tn / P;     // 256 timesteps per slab
constexpr int KC     = 16;         // chunks per slab
constexpr int CH     = SLAB / KC;  // 16 timesteps per chunk
constexpr int NT     = KC * G;     // 320 threads (5 waves)
constexpr int NCHUNK = Tn / CH;    // 256 chunks per row

__device__ __forceinline__ void nt_store4(float4* p, float a, float b,
                                          float c, float d) {
    f32x4 v = {a, b, c, d};
    __builtin_nontemporal_store(v, (f32x4*)p);
}

// ---------------- Kernel A: per-slab scan, write ALL per-chunk states -------
// One block per (b,p) slab. Phase 1: stream 16-step chunk EMA summaries.
// Phase 2: weighted Hillis-Steele over the 16 chunks in LDS (weight d^16,
// squared each round). Writes the slab-LOCAL inclusive state per chunk
// (2.6 MB) so kernel B does zero recomputation. (r4/r10-proven, ~14 us.)
__global__ __launch_bounds__(NT, 6)
void pcen_slabsum_kernel(const float* __restrict__ x,
                         const float* __restrict__ smooth,
                         float4* __restrict__ states)   // [Bn*NCHUNK*G]
{
    __shared__ float4 sc[2][KC][G];

    const int p  = blockIdx.x % P;
    const int b  = blockIdx.x / P;
    const int t  = threadIdx.x;
    const int g  = t % G;            // g fastest -> coalesced 320B runs
    const int kc = t / G;

    const float4 smv = ((const float4*)smooth)[g];
    float w0 = fminf(fmaxf(smv.x, 0.f), 1.f), w1 = fminf(fmaxf(smv.y, 0.f), 1.f);
    float w2 = fminf(fmaxf(smv.z, 0.f), 1.f), w3 = fminf(fmaxf(smv.w, 0.f), 1.f);
    float d0 = 1.f - w0, d1 = 1.f - w1, d2 = 1.f - w2, d3 = 1.f - w3;

    // d^16 via 4 squarings
    float q0 = d0 * d0, q1 = d1 * d1, q2 = d2 * d2, q3 = d3 * d3;
    q0 *= q0; q1 *= q1; q2 *= q2; q3 *= q3;
    q0 *= q0; q1 *= q1; q2 *= q2; q3 *= q3;
    q0 *= q0; q1 *= q1; q2 *= q2; q3 *= q3;

    const size_t rowbase = ((size_t)b * Tn + (size_t)p * SLAB + (size_t)kc * CH) * G + g;
    const float4* px = (const float4*)x + rowbase;

    // phase 1: chunk summary (fold init into very first chunk: e=x0 works
    // because d*x0 + w*x0 == x0)
    const bool fc = (p == 0) && (kc == 0);
    float e0, e1, e2, e3;
    if (fc) { float4 v = px[0]; e0 = v.x; e1 = v.y; e2 = v.z; e3 = v.w; }
    else    { e0 = 0.f; e1 = 0.f; e2 = 0.f; e3 = 0.f; }
    #pragma unroll
    for (int u = 0; u < CH; ++u) {
        float4 v = px[(size_t)u * G];
        e0 = fmaf(d0, e0, w0 * v.x);
        e1 = fmaf(d1, e1, w1 * v.y);
        e2 = fmaf(d2, e2, w2 * v.z);
        e3 = fmaf(d3, e3, w3 * v.w);
    }
    sc[0][kc][g] = make_float4(e0, e1, e2, e3);
    __syncthreads();

    // phase 2: weighted scan over chunks (W starts d^16, squared per round)
    float W0 = q0, W1 = q1, W2 = q2, W3 = q3;
    int src = 0;
    #pragma unroll
    for (int off = 1; off < KC; off <<= 1) {
        float4 v = sc[src][kc][g];
        if (kc >= off) {
            float4 u4 = sc[src][kc - off][g];
            v.x = fmaf(W0, u4.x, v.x);
            v.y = fmaf(W1, u4.y, v.y);
            v.z = fmaf(W2, u4.z, v.z);
            v.w = fmaf(W3, u4.w, v.w);
        }
        sc[src ^ 1][kc][g] = v;
        __syncthreads();
        src ^= 1;
        W0 *= W0; W1 *= W1; W2 *= W2; W3 *= W3;
    }

    // write every chunk's slab-local inclusive state, fully coalesced:
    // index = (b*NCHUNK + p*KC + kc)*G + g = blockIdx.x*NT + t
    states[(size_t)blockIdx.x * NT + t] = sc[src][kc][g];
}

// ---------------- Kernel B: coop row-prefix + streaming replay --------------
// One block per (b,p) slab, 320 threads (= one thread per (kc,g)).
// Prologue: cooperatively load the row's 16 slab summaries, 4-round
// Hillis-Steele in LDS with weight d^256 -> Sg[p'] (global-inclusive slab
// prefix). Each thread then forms its incoming state from ONE LDS read +
// ONE states load. Replay streams x (L3-warm from A; never retained in
// regs - r6/r12 spill lesson) and nontemporal-stores out.
__global__ __launch_bounds__(NT, 6)
void pcen_out_kernel(const float* __restrict__ x,
                     const float* __restrict__ alpha,
                     const float* __restrict__ delta,
                     const float* __restrict__ root,
                     const float* __restrict__ smooth,
                     const float4* __restrict__ states,
                     float* __restrict__ out)
{
    __shared__ float4 sS[2][KC][G];

    const int p  = blockIdx.x % P;
    const int b  = blockIdx.x / P;
    const int t  = threadIdx.x;
    const int g  = t % G;
    const int kc = t / G;            // doubles as p' in the prologue scan

    // ---- per-channel params ----
    const float4 smv = ((const float4*)smooth)[g];
    float w0 = fminf(fmaxf(smv.x, 0.f), 1.f), w1 = fminf(fmaxf(smv.y, 0.f), 1.f);
    float w2 = fminf(fmaxf(smv.z, 0.f), 1.f), w3 = fminf(fmaxf(smv.w, 0.f), 1.f);
    float d0 = 1.f - w0, d1 = 1.f - w1, d2 = 1.f - w2, d3 = 1.f - w3;

    // d^16 via 4 squarings
    float q0 = d0 * d0, q1 = d1 * d1, q2 = d2 * d2, q3 = d3 * d3;
    q0 *= q0; q1 *= q1; q2 *= q2; q3 *= q3;
    q0 *= q0; q1 *= q1; q2 *= q2; q3 *= q3;
    q0 *= q0; q1 *= q1; q2 *= q2; q3 *= q3;

    // ---- prologue: cooperative scan of the row's 16 slab summaries ----
    // thread (kc as p', g) loads slab p''s inclusive summary = states[.., kc=15]
    sS[0][kc][g] = states[((size_t)b * NCHUNK + kc * KC + (KC - 1)) * G + g];
    __syncthreads();

    // weight starts at d^256 (slab weight), squared each round
    float V0 = q0, V1 = q1, V2 = q2, V3 = q3;   // d^16
    V0 *= V0; V1 *= V1; V2 *= V2; V3 *= V3;     // d^32
    V0 *= V0; V1 *= V1; V2 *= V2; V3 *= V3;     // d^64
    V0 *= V0; V1 *= V1; V2 *= V2; V3 *= V3;     // d^128
    V0 *= V0; V1 *= V1; V2 *= V2; V3 *= V3;     // d^256
    int src = 0;
    #pragma unroll
    for (int off = 1; off < KC; off <<= 1) {
        float4 v = sS[src][kc][g];
        if (kc >= off) {
            float4 u4 = sS[src][kc - off][g];
            v.x = fmaf(V0, u4.x, v.x);
            v.y = fmaf(V1, u4.y, v.y);
            v.z = fmaf(V2, u4.z, v.z);
            v.w = fmaf(V3, u4.w, v.w);
        }
        sS[src ^ 1][kc][g] = v;
        __syncthreads();
        src ^= 1;
        V0 *= V0; V1 *= V1; V2 *= V2; V3 *= V3;
    }
    // sS[src][p'][g] = Sg[p'] = globally-inclusive state at end of slab p'

    // ---- incoming state for chunk (p,kc) ----
    const size_t sidx = ((size_t)b * NCHUNK + (size_t)p * KC + kc) * G + g;
    const size_t rowbase = ((size_t)b * Tn + ((size_t)p * KC + kc) * CH) * G + g;
    const float4* px = (const float4*)x + rowbase;

    float s0 = 0.f, s1 = 0.f, s2 = 0.f, s3 = 0.f;
    if (p > 0) {
        float4 Sg = sS[src][p - 1][g];
        s0 = Sg.x; s1 = Sg.y; s2 = Sg.z; s3 = Sg.w;
    }
    float m0, m1, m2, m3;
    if (kc == 0) {
        m0 = s0; m1 = s1; m2 = s2; m3 = s3;
    } else {
        float4 ex = states[sidx - G];   // slab-local inclusive of chunk kc-1
        // (d^16)^kc via square-and-multiply on 4 bits of kc
        float k0 = 1.f, k1 = 1.f, k2 = 1.f, k3 = 1.f;
        float b0 = q0, b1 = q1, b2 = q2, b3 = q3;
        int kk = kc;
        #pragma unroll
        for (int bit = 0; bit < 4; ++bit) {
            if (kk & 1) { k0 *= b0; k1 *= b1; k2 *= b2; k3 *= b3; }
            b0 *= b0; b1 *= b1; b2 *= b2; b3 *= b3;
            kk >>= 1;
        }
        m0 = fmaf(k0, s0, ex.x);
        m1 = fmaf(k1, s1, ex.y);
        m2 = fmaf(k2, s2, ex.z);
        m3 = fmaf(k3, s3, ex.w);
    }
    if ((p == 0) && (kc == 0)) {   // exact folded init: a_0 = x_0
        float4 v = px[0];
        m0 = v.x; m1 = v.y; m2 = v.z; m3 = v.w;
    }

    // ---- pointwise params ----
    const float4 alv = ((const float4*)alpha)[g];
    const float4 dlv = ((const float4*)delta)[g];
    const float4 rov = ((const float4*)root)[g];
    float nega[4], invr[4], dl[4], sub[4];
    {
        float as[4] = {alv.x, alv.y, alv.z, alv.w};
        float rs[4] = {rov.x, rov.y, rov.z, rov.w};
        dl[0] = dlv.x; dl[1] = dlv.y; dl[2] = dlv.z; dl[3] = dlv.w;
        #pragma unroll
        for (int j = 0; j < 4; ++j) {
            nega[j] = -fminf(as[j], 1.f);
            invr[j] = 1.f / fmaxf(rs[j], 1.f);
            sub[j]  = __expf(invr[j] * __logf(dl[j]));   // delta^(1/r)
        }
    }
    const bool all_sqrt = (invr[0] == 0.5f) & (invr[1] == 0.5f) &
                          (invr[2] == 0.5f) & (invr[3] == 0.5f);

    float4* po = (float4*)out + rowbase;

    // ---- replay: stream x, EMA, pointwise, nt store ----
    if (all_sqrt) {   // root == 2 fast path (wave-uniform)
        #pragma unroll
        for (int u = 0; u < CH; ++u) {
            float4 xv = px[(size_t)u * G];
            m0 = fmaf(d0, m0, w0 * xv.x);
            m1 = fmaf(d1, m1, w1 * xv.y);
            m2 = fmaf(d2, m2, w2 * xv.z);
            m3 = fmaf(d3, m3, w3 * xv.w);
            nt_store4(&po[(size_t)u * G],
                sqrtf(fmaf(xv.x, __expf(nega[0] * __logf(FLOOR_EPS + m0)), dl[0])) - sub[0],
                sqrtf(fmaf(xv.y, __expf(nega[1] * __logf(FLOOR_EPS + m1)), dl[1])) - sub[1],
                sqrtf(fmaf(xv.z, __expf(nega[2] * __logf(FLOOR_EPS + m2)), dl[2])) - sub[2],
                sqrtf(fmaf(xv.w, __expf(nega[3] * __logf(FLOOR_EPS + m3)), dl[3])) - sub[3]);
        }
    } else {
        float w[4] = {w0, w1, w2, w3}, dc[4] = {d0, d1, d2, d3};
        float mm[4] = {m0, m1, m2, m3};
        #pragma unroll
        for (int u = 0; u < CH; ++u) {
            float4 xv = px[(size_t)u * G];
            float xv4[4] = {xv.x, xv.y, xv.z, xv.w};
            float os[4];
            #pragma unroll
            for (int j = 0; j < 4; ++j) {
                mm[j]   = fmaf(dc[j], mm[j], w[j] * xv4[j]);
                float pw = __expf(nega[j] * __logf(FLOOR_EPS + mm[j]));
                float v  = fmaf(xv4[j], pw, dl[j]);
                os[j]    = __expf(invr[j] * __logf(v)) - sub[j];
            }
            nt_store4(&po[(size_t)u * G], os[0], os[1], os[2], os[3]);
        }
    }
}

extern "C" void kernel_launch(void* const* d_in, const int* in_sizes, int n_in,
                              void* d_out, int out_size, void* d_ws, size_t ws_size,
                              hipStream_t stream) {
    const float* x      = (const float*)d_in[0];
    const float* alpha  = (const float*)d_in[1];
    const float* delta  = (const float*)d_in[2];
    const float* root   = (const float*)d_in[3];
    const float* smooth = (const float*)d_in[4];
    float* out = (float*)d_out;

    float4* states = (float4*)d_ws;   // Bn*NCHUNK*G float4 = 2.62 MB

    pcen_slabsum_kernel<<<Bn * P, NT, 0, stream>>>(x, smooth, states);
    pcen_out_kernel<<<Bn * P, NT, 0, stream>>>(x, alpha, delta, root, smooth,
                                               states, out);
}